// Round 1
// baseline (517.401 us; speedup 1.0000x reference)
//
#include <hip/hip_runtime.h>

// CubicSplineUpsampling: (2,3,96,96,96) f32 -> (2,3,192,192,192) f32, factor 2.
//
// Stage 0: compute exact 96x96 prefilter matrix W in fp64 on device (unit-vector
//          simulation of the reference causal+anticausal recursion incl. boundary init).
// Stage 1-3: banded (|i-j|<=10) matvec along z, y, x axes. Truncation error ~1e-6.
// Stage 4: fused separable x2 upsampler through LDS (z->y->x), coalesced writes.

#define VOL (2 * 3 * 96 * 96 * 96)
#define BAND_R 10

__device__ float g_W[96 * 96];
__device__ float g_bufA[VOL];
__device__ float g_bufB[VOL];

// 8-tap cubic upsampling kernel split into 2 phases of 4 taps.
// phase 0 (even out): coarse offsets -2..+1 ; phase 1 (odd out): -1..+2
__device__ __constant__ float c_w[8] = {
    0.0026041666666666665f, 0.3151041666666666667f, 0.6119791666666666667f, 0.0703125f,
    0.0703125f, 0.6119791666666666667f, 0.3151041666666666667f, 0.0026041666666666665f
};

__global__ void compute_W_kernel(float* __restrict__ W) {
    int j = threadIdx.x;
    if (j >= 96) return;
    const double p = -0.26794919243112270647253365849413;  // sqrt(3)-2
    double c[96];
    // boundary constants (exact, as in reference)
    double pj = 1.0;
    for (int t = 0; t < j; ++t) pj *= p;
    double p191j = 1.0;
    for (int t = 0; t < 191 - j; ++t) p191j *= p;
    double p2n = 1.0;
    for (int t = 0; t < 192; ++t) p2n *= p;
    double K = p / (1.0 - p2n);
    // x = e_j, xm = 6*e_j
    double cur = 6.0 * K * (pj + p191j) + (j == 0 ? 6.0 : 0.0);
    c[0] = cur;
    for (int i = 1; i < 96; ++i) {
        cur = (i == j ? 6.0 : 0.0) + p * cur;
        c[i] = cur;
    }
    double nxt = cur * (p / (p - 1.0));
    W[95 * 96 + j] = (float)nxt;
    for (int i = 94; i >= 0; --i) {
        nxt = p * (nxt - c[i]);
        W[i * 96 + j] = (float)nxt;
    }
}

// Banded prefilter along an axis with element stride INNER. Layout: [o][96][INNER].
template <int INNER>
__global__ __launch_bounds__(256) void prefilter_kernel(const float* __restrict__ in,
                                                        float* __restrict__ out,
                                                        const float* __restrict__ W) {
    int idx = blockIdx.x * 256 + threadIdx.x;
    if (idx >= VOL) return;
    int r, q;
    if (INNER == 1) { r = 0; q = idx; }
    else { r = idx % INNER; q = idx / INNER; }
    int i = q % 96;
    int o = q / 96;
    const float* base = in + (size_t)o * 96 * INNER + r;
    const float* Wrow = W + i * 96;
    float sum = 0.0f;
#pragma unroll
    for (int d = -BAND_R; d <= BAND_R; ++d) {
        int j = i + d;
        if ((unsigned)j < 96u) sum += Wrow[j] * base[(size_t)j * INNER];
    }
    out[idx] = sum;
}

// Fused separable x2 upsampler. Block computes an 8x8x64 fine tile for one (n,c).
__global__ __launch_bounds__(256) void upsample_kernel(const float* __restrict__ cin,
                                                       float* __restrict__ out) {
    __shared__ float A[8 * 8 * 36];    // coarse tile (x,y,z)
    __shared__ float B[8 * 8 * 64];    // z-upsampled
    __shared__ float C2[8 * 8 * 64];   // y-upsampled
    int t = blockIdx.x;
    int tz = t % 3; t /= 3;
    int ty = t % 24;
    int tx = t / 24;
    int nc = blockIdx.y;
    int X0 = tx * 8, Y0 = ty * 8, Z0 = tz * 64;
    int cx0 = (X0 >> 1) - 2, cy0 = (Y0 >> 1) - 2, cz0 = (Z0 >> 1) - 2;
    const float* cb = cin + (size_t)nc * (96 * 96 * 96);
    int tid = threadIdx.x;

    // load coarse tile with clamped indices (== edge pad 2)
    for (int k = tid; k < 8 * 8 * 36; k += 256) {
        int cz = k % 36;
        int rest = k / 36;
        int cy = rest & 7;
        int cx = rest >> 3;
        int gx = min(max(cx0 + cx, 0), 95);
        int gy = min(max(cy0 + cy, 0), 95);
        int gz = min(max(cz0 + cz, 0), 95);
        A[(cx * 8 + cy) * 36 + cz] = cb[((size_t)gx * 96 + gy) * 96 + gz];
    }
    __syncthreads();

    // upsample z: A(8,8,36) -> B(8,8,64)
    for (int k = tid; k < 4096; k += 256) {
        int fz = k & 63;
        int cy = (k >> 6) & 7;
        int cx = k >> 9;
        int ph = fz & 1;
        int zb = (fz >> 1) + ph;
        const float* a = &A[(cx * 8 + cy) * 36 + zb];
        const float* w = &c_w[ph * 4];
        B[(cx * 8 + cy) * 64 + fz] = w[0] * a[0] + w[1] * a[1] + w[2] * a[2] + w[3] * a[3];
    }
    __syncthreads();

    // upsample y: B(8,8,64) -> C2(8,8,64) [cx, fy, fz]
    for (int k = tid; k < 4096; k += 256) {
        int fz = k & 63;
        int fy = (k >> 6) & 7;
        int cx = k >> 9;
        int ph = fy & 1;
        int yb = (fy >> 1) + ph;
        const float* b = &B[(cx * 8 + yb) * 64 + fz];
        const float* w = &c_w[ph * 4];
        C2[(cx * 8 + fy) * 64 + fz] = w[0] * b[0] + w[1] * b[64] + w[2] * b[128] + w[3] * b[192];
    }
    __syncthreads();

    // upsample x + store: C2(8,8,64) -> out(8x8x64 fine tile)
    for (int k = tid; k < 4096; k += 256) {
        int fz = k & 63;
        int fy = (k >> 6) & 7;
        int fx = k >> 9;
        int ph = fx & 1;
        int xb = (fx >> 1) + ph;
        const float* c2 = &C2[(xb * 8 + fy) * 64 + fz];
        const float* w = &c_w[ph * 4];
        float v = w[0] * c2[0] + w[1] * c2[512] + w[2] * c2[1024] + w[3] * c2[1536];
        out[(((size_t)nc * 192 + (X0 + fx)) * 192 + (Y0 + fy)) * 192 + (Z0 + fz)] = v;
    }
}

extern "C" void kernel_launch(void* const* d_in, const int* in_sizes, int n_in,
                              void* d_out, int out_size, void* d_ws, size_t ws_size,
                              hipStream_t stream) {
    const float* x = (const float*)d_in[0];
    float* out = (float*)d_out;
    float *W, *bufA, *bufB;
    hipGetSymbolAddress((void**)&W, HIP_SYMBOL(g_W));
    hipGetSymbolAddress((void**)&bufA, HIP_SYMBOL(g_bufA));
    hipGetSymbolAddress((void**)&bufB, HIP_SYMBOL(g_bufB));

    compute_W_kernel<<<1, 96, 0, stream>>>(W);

    int blocks = (VOL + 255) / 256;
    prefilter_kernel<1><<<blocks, 256, 0, stream>>>(x, bufA, W);        // z axis
    prefilter_kernel<96><<<blocks, 256, 0, stream>>>(bufA, bufB, W);    // y axis
    prefilter_kernel<96 * 96><<<blocks, 256, 0, stream>>>(bufB, bufA, W);  // x axis

    upsample_kernel<<<dim3(24 * 24 * 3, 6), 256, 0, stream>>>(bufA, out);
}